// Round 3
// baseline (11633.000 us; speedup 1.0000x reference)
//
#include <hip/hip_runtime.h>
#include <hip/hip_bf16.h>

#define TT 4096
#define BATCH 128
#define HID 64
#define CK 32              // chunk size
#define NCH (TT / CK)      // 128 chunks
#define NSLOT (NCH + 1)    // 129 checkpoint slots per (dir,b)

__device__ __forceinline__ float sigm(float x) { return 1.f / (1.f + expf(-x)); }
__device__ __forceinline__ float tanh_f(float x) { float e = expf(2.f * x); return 1.f - 2.f / (e + 1.f); }

// ---------------- Kernel A: layer-0 pass, store (h,c) checkpoints every CK steps ----------------
__global__ __launch_bounds__(256, 1) void lstm_ckpt(
    const float* __restrict__ x,      // [B][T][2]
    const float* __restrict__ w_ih,   // [2][256][2]
    const float* __restrict__ w_hh,   // [2][256][64]
    const float* __restrict__ b_ih, const float* __restrict__ b_hh,
    float* __restrict__ ckpt)         // [2][B][NSLOT][128] (h:0..63, c:64..127)
{
    const int blk = blockIdx.x;
    const int dir = blk & 1;
    const int b   = blk >> 1;
    const int tid = threadIdx.x;

    __shared__ __align__(16) float xs[TT * 2];
    __shared__ __align__(16) float h_lds[HID];
    __shared__ __align__(16) float g_lds[256];

    {
        const float4* src = (const float4*)(x + (size_t)b * TT * 2);
        float4* dst = (float4*)xs;
        #pragma unroll
        for (int r = 0; r < 8; ++r) dst[tid + r * 256] = src[tid + r * 256];
    }
    const int row = dir * 256 + tid;
    float wv[HID];
    {
        const float4* wr = (const float4*)(w_hh + (size_t)row * HID);
        #pragma unroll
        for (int k = 0; k < 16; ++k) {
            float4 v = wr[k];
            wv[4*k] = v.x; wv[4*k+1] = v.y; wv[4*k+2] = v.z; wv[4*k+3] = v.w;
        }
    }
    const float wx0 = w_ih[row * 2 + 0], wx1 = w_ih[row * 2 + 1];
    const float bias = b_ih[row] + b_hh[row];
    const int gtype = tid >> 6;
    float c = 0.f, hreg = 0.f;
    if (tid < HID) h_lds[tid] = 0.f;
    __syncthreads();

    for (int t = 0; t < TT; ++t) {
        const int tt = dir ? (TT - 1 - t) : t;
        if (tid < HID) {
            const int bnum = dir ? (tt + 1) : tt;   // state BEFORE processing tt
            if ((bnum & (CK - 1)) == 0) {
                float* cp = ckpt + (((size_t)(dir * BATCH + b) * NSLOT + (bnum >> 5)) << 7);
                cp[tid] = hreg; cp[HID + tid] = c;
            }
        }
        const float base = bias + wx0 * xs[tt * 2] + wx1 * xs[tt * 2 + 1];
        float a0 = 0.f, a1 = 0.f, a2 = 0.f, a3 = 0.f;
        const float4* h4 = (const float4*)h_lds;
        #pragma unroll
        for (int k = 0; k < 16; ++k) {
            float4 hv = h4[k];
            a0 = fmaf(wv[4*k],   hv.x, a0);
            a1 = fmaf(wv[4*k+1], hv.y, a1);
            a2 = fmaf(wv[4*k+2], hv.z, a2);
            a3 = fmaf(wv[4*k+3], hv.w, a3);
        }
        const float acc = base + ((a0 + a1) + (a2 + a3));
        g_lds[tid] = (gtype == 2) ? tanh_f(acc) : sigm(acc);
        __syncthreads();
        if (tid < HID) {
            const float iv = g_lds[tid], fv = g_lds[64 + tid], gg = g_lds[128 + tid], ov = g_lds[192 + tid];
            c = fv * c + iv * gg;
            hreg = ov * tanh_f(c);
            h_lds[tid] = hreg;
        }
        __syncthreads();
    }
}

// ---------------- Kernel B: fused layer-1 + layer-0 recompute + FC logits (512 threads) ----------------
// tid<256: L1, thread = gate row (192 weights in VGPRs).
// tid>=256: t0=tid-256. Gate role: dir dg=t0>>7, rows jg=t0&127 and jg+128 (132 weights).
//           Update role (t0<128): dir du=t0>>6, elem eu=t0&63 holds c-state.
//           t0 in [128,192): logits wave. t0 in [192,208): x prefetch.
__global__ __launch_bounds__(512, 2) void lstm_fused1(
    const float* __restrict__ x,
    const float* __restrict__ w_ih0, const float* __restrict__ w_hh0,
    const float* __restrict__ b_ih0, const float* __restrict__ b_hh0,
    const float* __restrict__ w_ih1, const float* __restrict__ w_hh1,
    const float* __restrict__ b_ih1, const float* __restrict__ b_hh1,
    const float* __restrict__ fc_w,  const float* __restrict__ ckpt,
    float* __restrict__ plog)        // [2][B][T][2]
{
    const int blk = blockIdx.x;
    const int l1dir = blk & 1;
    const int b = blk >> 1;
    const int tid = threadIdx.x;

    __shared__ __align__(16) float h0buf[2][CK][128];
    __shared__ __align__(16) float xbuf[2][CK][2];
    __shared__ __align__(16) float g1[256];
    __shared__ __align__(16) float g0[2][256];
    __shared__ __align__(16) float h1b[2][HID];
    __shared__ __align__(16) float h0s[2][HID];

    const bool isL1 = (tid < 256);
    const int t0 = tid - 256;
    const int dg = t0 >> 7;
    const int jg = t0 & 127;
    const int du = t0 >> 6;        // valid when t0 < 128
    const int eu = t0 & 63;

    float wreg[192];               // overlaid: L1 wi[0..127]+wh[128..191]; L0 whA[0..63]+whB[64..127]+wx[128..131]
    float bias0 = 0.f, bias1 = 0.f;
    float fw0 = 0.f, fw1 = 0.f;
    float c_st = 0.f;              // L1 c (tid<64) or L0 c (t0<128)
    float ckh = 0.f, ckc = 0.f;
    float4 xpre = make_float4(0.f, 0.f, 0.f, 0.f);

    if (isL1) {
        const int grow = l1dir * 256 + tid;
        const float4* wia = (const float4*)(w_ih1 + (size_t)grow * 128);
        #pragma unroll
        for (int k = 0; k < 32; ++k) {
            float4 v = wia[k];
            wreg[4*k] = v.x; wreg[4*k+1] = v.y; wreg[4*k+2] = v.z; wreg[4*k+3] = v.w;
        }
        const float4* wha = (const float4*)(w_hh1 + (size_t)grow * 64);
        #pragma unroll
        for (int k = 0; k < 16; ++k) {
            float4 v = wha[k];
            wreg[128+4*k] = v.x; wreg[128+4*k+1] = v.y; wreg[128+4*k+2] = v.z; wreg[128+4*k+3] = v.w;
        }
        bias0 = b_ih1[grow] + b_hh1[grow];
    } else {
        const int rA = dg * 256 + jg;
        const int rB = rA + 128;
        const float4* wa = (const float4*)(w_hh0 + (size_t)rA * 64);
        const float4* wb = (const float4*)(w_hh0 + (size_t)rB * 64);
        #pragma unroll
        for (int k = 0; k < 16; ++k) {
            float4 v = wa[k];
            wreg[4*k] = v.x; wreg[4*k+1] = v.y; wreg[4*k+2] = v.z; wreg[4*k+3] = v.w;
        }
        #pragma unroll
        for (int k = 0; k < 16; ++k) {
            float4 v = wb[k];
            wreg[64+4*k] = v.x; wreg[64+4*k+1] = v.y; wreg[64+4*k+2] = v.z; wreg[64+4*k+3] = v.w;
        }
        wreg[128] = w_ih0[rA * 2 + 0]; wreg[129] = w_ih0[rA * 2 + 1];
        wreg[130] = w_ih0[rB * 2 + 0]; wreg[131] = w_ih0[rB * 2 + 1];
        bias0 = b_ih0[rA] + b_hh0[rA];
        bias1 = b_ih0[rB] + b_hh0[rB];
        if (t0 >= 128 && t0 < 192) {
            fw0 = fc_w[l1dir * 64 + (t0 - 128)];
            fw1 = fc_w[128 + l1dir * 64 + (t0 - 128)];
        }
    }

    // initial state: h1=0; chunk-0 x and ckpt
    if (tid < HID) { h1b[0][tid] = 0.f; h1b[1][tid] = 0.f; }
    {
        const int ch0 = l1dir ? (NCH - 1) : 0;
        if (!isL1 && t0 >= 192 && t0 < 208)
            ((float4*)xbuf[0])[t0 - 192] = ((const float4*)(x + ((size_t)b * TT + (size_t)ch0 * CK) * 2))[t0 - 192];
        if (!isL1 && t0 < 128) {
            const int slot = du ? (ch0 + 1) : ch0;
            const float* cp = ckpt + (((size_t)(du * BATCH + b) * NSLOT + slot) << 7);
            h0s[du][eu] = cp[eu];
            c_st = cp[HID + eu];
        }
    }
    __syncthreads();

    auto stepf = [&](int s, int ml, int mc, int mp) {
        const int u = ml * CK + s;   // only meaningful when ml >= 0
        // ---------- phase A: gate dots + prefetch ----------
        if (s == 0 && mp >= 0 && !isL1) {
            const int chp = l1dir ? (NCH - 1 - mp) : mp;
            if (t0 < 128) {
                const int slot = du ? (chp + 1) : chp;
                const float* cp = ckpt + (((size_t)(du * BATCH + b) * NSLOT + slot) << 7);
                ckh = cp[eu]; ckc = cp[HID + eu];
            }
            if (t0 >= 192 && t0 < 208)
                xpre = ((const float4*)(x + ((size_t)b * TT + (size_t)chp * CK) * 2))[t0 - 192];
        }
        if (isL1) {
            if (ml >= 0) {
                const int trow = l1dir ? (CK - 1 - s) : s;
                const float4* p4 = (const float4*)h0buf[ml & 1][trow];
                float a0 = 0.f, a1 = 0.f, a2 = 0.f, a3 = 0.f;
                #pragma unroll
                for (int k = 0; k < 32; ++k) {
                    float4 v = p4[k];
                    a0 = fmaf(wreg[4*k],   v.x, a0);
                    a1 = fmaf(wreg[4*k+1], v.y, a1);
                    a2 = fmaf(wreg[4*k+2], v.z, a2);
                    a3 = fmaf(wreg[4*k+3], v.w, a3);
                }
                const float4* h14 = (const float4*)h1b[u & 1];
                #pragma unroll
                for (int k = 0; k < 16; ++k) {
                    float4 v = h14[k];
                    a0 = fmaf(wreg[128+4*k],   v.x, a0);
                    a1 = fmaf(wreg[128+4*k+1], v.y, a1);
                    a2 = fmaf(wreg[128+4*k+2], v.z, a2);
                    a3 = fmaf(wreg[128+4*k+3], v.w, a3);
                }
                const float acc = bias0 + ((a0 + a1) + (a2 + a3));
                g1[tid] = ((tid >> 6) == 2) ? tanh_f(acc) : sigm(acc);
            }
        } else if (mc >= 0) {
            const int r0 = dg ? (CK - 1 - s) : s;
            const float4* hp = (const float4*)h0s[dg];
            float a0 = 0.f, a1 = 0.f, a2 = 0.f, a3 = 0.f;
            float e0 = 0.f, e1 = 0.f, e2 = 0.f, e3 = 0.f;
            #pragma unroll
            for (int k = 0; k < 16; ++k) {
                float4 v = hp[k];
                a0 = fmaf(wreg[4*k],   v.x, a0);
                a1 = fmaf(wreg[4*k+1], v.y, a1);
                a2 = fmaf(wreg[4*k+2], v.z, a2);
                a3 = fmaf(wreg[4*k+3], v.w, a3);
                e0 = fmaf(wreg[64+4*k],   v.x, e0);
                e1 = fmaf(wreg[64+4*k+1], v.y, e1);
                e2 = fmaf(wreg[64+4*k+2], v.z, e2);
                e3 = fmaf(wreg[64+4*k+3], v.w, e3);
            }
            const float xv0 = xbuf[mc & 1][r0][0], xv1 = xbuf[mc & 1][r0][1];
            const float accA = bias0 + ((a0 + a1) + (a2 + a3)) + wreg[128] * xv0 + wreg[129] * xv1;
            const float accB = bias1 + ((e0 + e1) + (e2 + e3)) + wreg[130] * xv0 + wreg[131] * xv1;
            g0[dg][jg]       = sigm(accA);                       // rows 0..127: i,f gates
            g0[dg][jg + 128] = (jg < 64) ? tanh_f(accB) : sigm(accB);  // g rows tanh, o rows sigm
        }
        __syncthreads();
        // ---------- phase B: state updates, logits, staging ----------
        if (isL1) {
            if (ml >= 0 && tid < 64) {
                const float iv = g1[tid], fv = g1[64 + tid], gg = g1[128 + tid], ov = g1[192 + tid];
                c_st = fv * c_st + iv * gg;
                h1b[(u + 1) & 1][tid] = ov * tanh_f(c_st);
            }
        } else {
            if (mc >= 0 && t0 < 128) {
                const float iv = g0[du][eu], fv = g0[du][64 + eu], gg = g0[du][128 + eu], ov = g0[du][192 + eu];
                c_st = fv * c_st + iv * gg;
                const float hv = ov * tanh_f(c_st);
                const int orow = du ? (CK - 1 - s) : s;
                h0buf[mc & 1][orow][du * 64 + eu] = hv;
                if (s == CK - 1 && mp >= 0) { h0s[du][eu] = ckh; c_st = ckc; }
                else h0s[du][eu] = hv;
            }
            if (ml >= 0 && t0 >= 128 && t0 < 192) {
                if (u > 0) {
                    const int l = t0 - 128;
                    const float hv = h1b[u & 1][l];
                    float p0 = hv * fw0, p1 = hv * fw1;
                    #pragma unroll
                    for (int d_ = 32; d_ > 0; d_ >>= 1) { p0 += __shfl_xor(p0, d_); p1 += __shfl_xor(p1, d_); }
                    if (l == 0) {
                        const int tp = l1dir ? (TT - u) : (u - 1);
                        *(float2*)(plog + (((size_t)l1dir * BATCH + b) * TT + tp) * 2) = make_float2(p0, p1);
                    }
                }
            }
            if (s == CK - 1 && mp >= 0 && t0 >= 192 && t0 < 208)
                ((float4*)xbuf[mp & 1])[t0 - 192] = xpre;
        }
        __syncthreads();
    };

    // prologue: L0 computes chunk 0 into buf0; prefetch chunk 1
    for (int s = 0; s < CK; ++s) stepf(s, -1, 0, 1);
    // main: L1 consumes chunk i; L0 computes i+1; prefetch i+2
    for (int i = 0; i < NCH; ++i) {
        const int mc = (i + 1 < NCH) ? (i + 1) : -1;
        const int mp = (i + 2 < NCH) ? (i + 2) : -1;
        for (int s = 0; s < CK; ++s) stepf(s, i, mc, mp);
    }
    // final logit (u = TT), h1b[TT&1] = h1b[0]
    if (!isL1 && t0 >= 128 && t0 < 192) {
        const int l = t0 - 128;
        const float hv = h1b[0][l];
        float p0 = hv * fw0, p1 = hv * fw1;
        #pragma unroll
        for (int d_ = 32; d_ > 0; d_ >>= 1) { p0 += __shfl_xor(p0, d_); p1 += __shfl_xor(p1, d_); }
        if (l == 0) {
            const int tp = l1dir ? 0 : (TT - 1);
            *(float2*)(plog + (((size_t)l1dir * BATCH + b) * TT + tp) * 2) = make_float2(p0, p1);
        }
    }
}

// ---------------- Kernel C: fused Viterbi (max-plus parallel scan + backtrack) ----------------
__device__ __forceinline__ unsigned long long shfl_u64(unsigned long long v, int src) {
    unsigned int lo = (unsigned int)v, hi = (unsigned int)(v >> 32);
    lo = __shfl(lo, src); hi = __shfl(hi, src);
    return ((unsigned long long)hi << 32) | lo;
}

__global__ __launch_bounds__(64, 1) void viterbi_k(
    const float* __restrict__ plog, const float* __restrict__ fc_b,
    const float* __restrict__ trans, const float* __restrict__ startv,
    const float* __restrict__ endv, int* __restrict__ out)
{
    const int b = blockIdx.x;
    const int lane = threadIdx.x;
    __shared__ __align__(16) float2 e_lds[64][65];   // [t&63][t>>6], padded

    const float fb0 = fc_b[0], fb1 = fc_b[1];
    const float* pf = plog + ((size_t)(0 * BATCH + b) * TT) * 2;
    const float* pb = plog + ((size_t)(1 * BATCH + b) * TT) * 2;
    for (int r = 0; r < 32; ++r) {
        const int i4 = r * 64 + lane;            // covers t = 2*i4, 2*i4+1
        float4 a = ((const float4*)pf)[i4];
        float4 cc = ((const float4*)pb)[i4];
        const int t0 = 2 * i4, t1 = t0 + 1;
        e_lds[t0 & 63][t0 >> 6] = make_float2(a.x + cc.x + fb0, a.y + cc.y + fb1);
        e_lds[t1 & 63][t1 >> 6] = make_float2(a.z + cc.z + fb0, a.w + cc.w + fb1);
    }
    __syncthreads();
    const float tr00 = trans[0], tr01 = trans[1], tr10 = trans[2], tr11 = trans[3];
    const float2 e0 = e_lds[0][0];
    const float s00 = startv[0] + e0.x, s01 = startv[1] + e0.y;   // score at t=0

    const int lo = lane * 64;
    const int hi = (lane == 63) ? (TT - 1) : (lo + 64);
    // pass 1: chunk max-plus matrix A (maps score@lo -> score@hi)
    float a00, a01, a10, a11;
    {
        const float2 ee = e_lds[(lo + 1) & 63][(lo + 1) >> 6];
        a00 = tr00 + ee.x; a01 = tr01 + ee.y; a10 = tr10 + ee.x; a11 = tr11 + ee.y;
    }
    for (int t = lo + 2; t <= hi; ++t) {
        const float2 ee = e_lds[t & 63][t >> 6];
        const float n00 = fmaxf(a00 + tr00, a01 + tr10) + ee.x;
        const float n01 = fmaxf(a00 + tr01, a01 + tr11) + ee.y;
        const float n10 = fmaxf(a10 + tr00, a11 + tr10) + ee.x;
        const float n11 = fmaxf(a10 + tr01, a11 + tr11) + ee.y;
        a00 = n00; a01 = n01; a10 = n10; a11 = n11;
    }
    // inclusive scan: lane i -> A_0 ∘ ... ∘ A_i  (earlier left)
    #pragma unroll
    for (int d = 1; d < 64; d <<= 1) {
        const float o00 = __shfl_up(a00, d), o01 = __shfl_up(a01, d);
        const float o10 = __shfl_up(a10, d), o11 = __shfl_up(a11, d);
        if (lane >= d) {
            const float n00 = fmaxf(o00 + a00, o01 + a10);
            const float n01 = fmaxf(o00 + a01, o01 + a11);
            const float n10 = fmaxf(o10 + a00, o11 + a10);
            const float n11 = fmaxf(o10 + a01, o11 + a11);
            a00 = n00; a01 = n01; a10 = n10; a11 = n11;
        }
    }
    // entry score at t=lo
    const float p00 = __shfl_up(a00, 1), p01 = __shfl_up(a01, 1);
    const float p10 = __shfl_up(a10, 1), p11 = __shfl_up(a11, 1);
    float s0, s1;
    if (lane == 0) { s0 = s00; s1 = s01; }
    else { s0 = fmaxf(s00 + p00, s01 + p10); s1 = fmaxf(s00 + p01, s01 + p11); }
    // re-walk, record bp bits (bit s = decision at t=lo+1+s)
    unsigned long long m0 = 0ull, m1 = 0ull;
    for (int t = lo + 1; t <= hi; ++t) {
        const float2 ee = e_lds[t & 63][t >> 6];
        const float c00 = s0 + tr00, c10 = s1 + tr10;
        const float c01 = s0 + tr01, c11 = s1 + tr11;
        const int bp0 = c10 > c00, bp1 = c11 > c01;   // strict >: first-index tiebreak
        s0 = (bp0 ? c10 : c00) + ee.x;
        s1 = (bp1 ? c11 : c01) + ee.y;
        m0 |= (unsigned long long)bp0 << (t - lo - 1);
        m1 |= (unsigned long long)bp1 << (t - lo - 1);
    }
    // last tag (lane 63 holds final scores)
    int last;
    {
        const int lt = (s1 + endv[1]) > (s0 + endv[0]);
        last = __shfl(lt, 63);
    }
    // chunk map F: tag@hi -> tag@lo
    int f0 = 0, f1 = 1;
    for (int t = hi; t > lo; --t) {
        const int s_ = t - lo - 1;
        f0 = (int)(((f0 ? m1 : m0) >> s_) & 1ull);
        f1 = (int)(((f1 ? m1 : m0) >> s_) & 1ull);
    }
    int mm = f0 | (f1 << 1);
    // suffix scan: G_i = F_i ∘ G_{i+d}
    #pragma unroll
    for (int d = 1; d < 64; d <<= 1) {
        const int mo = __shfl_down(mm, d);
        if (lane + d < 64) {
            const int r0 = (mm >> (mo & 1)) & 1;
            const int r1 = (mm >> ((mo >> 1) & 1)) & 1;
            mm = r0 | (r1 << 1);
        }
    }
    const int gn = __shfl_down(mm, 1);
    int cur = (lane == 63) ? last : ((gn >> last) & 1);   // tag at t=hi
    unsigned long long tagm = 0ull;                        // bit s = tag at t=lo+s
    if (lane == 63) tagm |= (unsigned long long)last << 63;
    for (int t = hi; t > lo; --t) {
        const int s_ = t - lo - 1;
        cur = (int)(((cur ? m1 : m0) >> s_) & 1ull);
        tagm |= (unsigned long long)cur << s_;
    }
    // output: t = r*64 + lane -> lane r's bit 'lane'
    int* ob = out + (size_t)b * TT;
    for (int r = 0; r < 64; ++r) {
        const unsigned long long mr = shfl_u64(tagm, r);
        ob[r * 64 + lane] = (int)((mr >> lane) & 1ull);
    }
}

extern "C" void kernel_launch(void* const* d_in, const int* in_sizes, int n_in,
                              void* d_out, int out_size, void* d_ws, size_t ws_size,
                              hipStream_t stream) {
    const float* x      = (const float*)d_in[0];
    const float* w_ih0  = (const float*)d_in[1];
    const float* w_hh0  = (const float*)d_in[2];
    const float* b_ih0  = (const float*)d_in[3];
    const float* b_hh0  = (const float*)d_in[4];
    const float* w_ih1  = (const float*)d_in[5];
    const float* w_hh1  = (const float*)d_in[6];
    const float* b_ih1  = (const float*)d_in[7];
    const float* b_hh1  = (const float*)d_in[8];
    const float* fc_w   = (const float*)d_in[9];
    const float* fc_b   = (const float*)d_in[10];
    const float* trans  = (const float*)d_in[11];
    const float* startv = (const float*)d_in[12];
    const float* endv   = (const float*)d_in[13];

    char* ws = (char*)d_ws;
    const size_t ckpt_bytes = (size_t)2 * BATCH * NSLOT * 128 * 4;   // ~16.9 MB
    float* ckpt = (float*)ws;
    float* plog = (float*)(ws + ckpt_bytes);                          // 8 MB

    lstm_ckpt<<<256, 256, 0, stream>>>(x, w_ih0, w_hh0, b_ih0, b_hh0, ckpt);
    lstm_fused1<<<256, 512, 0, stream>>>(x, w_ih0, w_hh0, b_ih0, b_hh0,
                                         w_ih1, w_hh1, b_ih1, b_hh1,
                                         fc_w, ckpt, plog);
    viterbi_k<<<128, 64, 0, stream>>>(plog, fc_b, trans, startv, endv, (int*)d_out);
}

// Round 4
// 8276.078 us; speedup vs baseline: 1.4056x; 1.4056x over previous
//
#include <hip/hip_runtime.h>

#define TT 4096
#define BATCH 128
#define HID 64
#define CK 32              // chunk size
#define NCH (TT / CK)      // 128 chunks
#define NSLOT (NCH + 1)    // 129 checkpoint slots per (dir,b)

__device__ __forceinline__ float sigm(float x) { return 1.f / (1.f + expf(-x)); }
__device__ __forceinline__ float tanh_f(float x) { float e = expf(2.f * x); return 1.f - 2.f / (e + 1.f); }

// ---------------- Kernel A: layer-0 pass, 2 threads/row, store (h,c) ckpt every CK steps ----------------
__global__ __launch_bounds__(512) __attribute__((amdgpu_waves_per_eu(2, 2))) void lstm_ckpt(
    const float* __restrict__ x,      // [B][T][2]
    const float* __restrict__ w_ih,   // [2][256][2]
    const float* __restrict__ w_hh,   // [2][256][64]
    const float* __restrict__ b_ih, const float* __restrict__ b_hh,
    float* __restrict__ ckpt)         // [2][B][NSLOT][128] (h:0..63, c:64..127)
{
    const int blk = blockIdx.x;
    const int dir = blk & 1;
    const int b   = blk >> 1;
    const int tid = threadIdx.x;
    const int row = tid >> 1, half = tid & 1;

    __shared__ __align__(16) float xs[TT * 2];
    __shared__ __align__(16) float h_lds[HID];
    __shared__ __align__(16) float g_lds[256];

    {   // stage x[b] (32 KB)
        const float4* src = (const float4*)(x + (size_t)b * TT * 2);
        float4* dst = (float4*)xs;
        for (int rr = tid; rr < 2048; rr += 512) dst[rr] = src[rr];
    }
    const int grow = dir * 256 + row;
    float wv[32];
    {
        const float4* wr = (const float4*)(w_hh + (size_t)grow * 64) + half * 8;
        #pragma unroll
        for (int k = 0; k < 8; ++k) {
            float4 v = wr[k];
            wv[4*k] = v.x; wv[4*k+1] = v.y; wv[4*k+2] = v.z; wv[4*k+3] = v.w;
        }
    }
    const float wx0 = half ? 0.f : w_ih[grow * 2 + 0];
    const float wx1 = half ? 0.f : w_ih[grow * 2 + 1];
    const float bias = half ? 0.f : (b_ih[grow] + b_hh[grow]);
    const int gtype = row >> 6;
    float c = 0.f, hreg = 0.f;
    if (tid < HID) h_lds[tid] = 0.f;
    __syncthreads();

    for (int t = 0; t < TT; ++t) {
        const int tt = dir ? (TT - 1 - t) : t;
        if (tid < HID) {   // state BEFORE processing tt
            const int bnum = dir ? (tt + 1) : tt;
            if ((bnum & (CK - 1)) == 0) {
                float* cp = ckpt + (((size_t)(dir * BATCH + b) * NSLOT + (bnum >> 5)) << 7);
                cp[tid] = hreg; cp[HID + tid] = c;
            }
        }
        const float4* h4 = (const float4*)h_lds + half * 8;
        float a0 = 0.f, a1 = 0.f, a2 = 0.f, a3 = 0.f;
        #pragma unroll
        for (int k = 0; k < 8; ++k) {
            float4 hv = h4[k];
            a0 = fmaf(wv[4*k],   hv.x, a0);
            a1 = fmaf(wv[4*k+1], hv.y, a1);
            a2 = fmaf(wv[4*k+2], hv.z, a2);
            a3 = fmaf(wv[4*k+3], hv.w, a3);
        }
        float tot = (a0 + a1) + (a2 + a3);
        tot += __shfl_xor(tot, 1);
        if (half == 0) {
            const float acc = tot + bias + wx0 * xs[tt * 2] + wx1 * xs[tt * 2 + 1];
            g_lds[row] = (gtype == 2) ? tanh_f(acc) : sigm(acc);
        }
        __syncthreads();
        if (tid < HID) {
            const float iv = g_lds[tid], fv = g_lds[64 + tid], gg = g_lds[128 + tid], ov = g_lds[192 + tid];
            c = fv * c + iv * gg;
            hreg = ov * tanh_f(c);
            h_lds[tid] = hreg;
        }
        __syncthreads();
    }
}

// ---------------- Kernel B: fused L1-serial + chunk GEMM (wi1*h0) + L0 recompute + logits ----------------
// 1024 threads: [0,256) L1-serial (wh1[64]); [256,768) L0 (wh0[64]+wx[2]); [768,1024) GEMM (acc[32] in r[]).
__global__ __attribute__((amdgpu_flat_work_group_size(1024, 1024), amdgpu_waves_per_eu(4, 4)))
void lstm_fused1(
    const float* __restrict__ x,
    const float* __restrict__ w_ih0, const float* __restrict__ w_hh0,
    const float* __restrict__ b_ih0, const float* __restrict__ b_hh0,
    const float* __restrict__ w_ih1, const float* __restrict__ w_hh1,
    const float* __restrict__ b_ih1, const float* __restrict__ b_hh1,
    const float* __restrict__ fc_w,  const float* __restrict__ ckpt,
    float* __restrict__ plog)        // [2][B][T][2]
{
    const int blk = blockIdx.x;
    const int l1dir = blk & 1;
    const int b = blk >> 1;
    const int tid = threadIdx.x;

    __shared__ __align__(16) float h0buf[2][CK][128];   // 32 KB
    __shared__ __align__(16) float xg1[2][CK][256];     // 64 KB
    __shared__ __align__(16) float xbuf[2][CK][2];
    __shared__ __align__(16) float g1[256];
    __shared__ __align__(16) float g0[2][256];
    __shared__ __align__(16) float h1b[2][HID];
    __shared__ __align__(16) float h0s[2][HID];

    const bool isL1 = tid < 256;
    const bool isL0 = (tid >= 256) && (tid < 768);
    const bool isG  = tid >= 768;
    const int q0 = tid - 256;
    const int d0 = (q0 >> 8) & 1;   // L0 dir
    const int j0 = q0 & 255;        // L0 gate row
    const int jg = (tid - 768) & 255;

    float r[64];                    // L1/L0: weights; GEMM: r[0..31] accumulators
    float bias_ = 0.f, wx0 = 0.f, wx1 = 0.f, fw0 = 0.f, fw1 = 0.f;
    float c1 = 0.f, c0 = 0.f, ckh = 0.f, ckc = 0.f;
    float4 xpre = make_float4(0.f, 0.f, 0.f, 0.f);
    float4 wc = make_float4(0.f, 0.f, 0.f, 0.f);
    const float4* wip4 = (const float4*)(w_ih1 + (size_t)(l1dir * 256 + jg) * 128);

    if (isL1) {
        const int grow = l1dir * 256 + tid;
        const float4* wr = (const float4*)(w_hh1 + (size_t)grow * 64);
        #pragma unroll
        for (int k = 0; k < 16; ++k) {
            float4 v = wr[k];
            r[4*k] = v.x; r[4*k+1] = v.y; r[4*k+2] = v.z; r[4*k+3] = v.w;
        }
        bias_ = b_ih1[grow] + b_hh1[grow];
        if (tid >= 64 && tid < 128) {
            fw0 = fc_w[l1dir * 64 + (tid - 64)];
            fw1 = fc_w[128 + l1dir * 64 + (tid - 64)];
        }
    } else if (isL0) {
        const int grow = d0 * 256 + j0;
        const float4* wr = (const float4*)(w_hh0 + (size_t)grow * 64);
        #pragma unroll
        for (int k = 0; k < 16; ++k) {
            float4 v = wr[k];
            r[4*k] = v.x; r[4*k+1] = v.y; r[4*k+2] = v.z; r[4*k+3] = v.w;
        }
        wx0 = w_ih0[grow * 2 + 0];
        wx1 = w_ih0[grow * 2 + 1];
        bias_ = b_ih0[grow] + b_hh0[grow];
    } else {
        #pragma unroll
        for (int k = 0; k < 32; ++k) r[k] = 0.f;
        wc = wip4[0];
    }

    // init: h1 state, chunk-0 ckpt, chunk-0 x
    if (tid < HID) { h1b[0][tid] = 0.f; h1b[1][tid] = 0.f; }
    {
        const int ac0 = l1dir ? (NCH - 1) : 0;
        if (tid < 16)
            ((float4*)xbuf[0])[tid] = ((const float4*)(x + ((size_t)b * TT + (size_t)ac0 * CK) * 2))[tid];
        if (isL0 && j0 < 64) {
            const int slot = d0 ? (ac0 + 1) : ac0;
            const float* cp = ckpt + (((size_t)(d0 * BATCH + b) * NSLOT + slot) << 7);
            h0s[d0][j0] = cp[j0];
            c0 = cp[HID + j0];
        }
    }
    __syncthreads();

    // phase i: L1 consumes seq-chunk i; GEMM builds xg1 for chunk i+1 from h0buf[(i+1)&1];
    //          L0 computes chunk i+2 into h0buf[i&1]; prefetch ckpt/x for chunk i+3.
    for (int i = -2; i < NCH; ++i) {
        const bool l1act = i >= 0;
        const bool gact  = (i + 1 >= 0) && (i + 1 < NCH);
        const bool l0act = (i + 2) < NCH;
        const int hbL0 = i & 1;
        const int hbG  = (i + 1) & 1;
        for (int s = 0; s < CK; ++s) {
            // ======== phase A ========
            if (isG) {
                if (gact) {
                    float4 wn = wip4[(s + 1) & (CK - 1)];
                    const float4* hb = (const float4*)&h0buf[hbG][0][0] + s;   // row stride 32 float4
                    #pragma unroll
                    for (int s2 = 0; s2 < 32; ++s2) {
                        float4 hv = hb[s2 * 32];
                        float t0 = r[s2];
                        t0 = fmaf(wc.x, hv.x, t0);
                        t0 = fmaf(wc.y, hv.y, t0);
                        t0 = fmaf(wc.z, hv.z, t0);
                        t0 = fmaf(wc.w, hv.w, t0);
                        r[s2] = t0;
                    }
                    if (s == CK - 1) {
                        #pragma unroll
                        for (int s2 = 0; s2 < 32; ++s2) { xg1[hbG][s2][jg] = r[s2]; r[s2] = 0.f; }
                    }
                    wc = wn;
                }
            } else if (isL0) {
                if (s == 0 && j0 < 64 && (i + 3) < NCH) {
                    const int acn = l1dir ? (NCH - 1 - (i + 3)) : (i + 3);
                    const int slot = d0 ? (acn + 1) : acn;
                    const float* cp = ckpt + (((size_t)(d0 * BATCH + b) * NSLOT + slot) << 7);
                    ckh = cp[j0]; ckc = cp[HID + j0];
                }
                if (l0act) {
                    const int orow = d0 ? (CK - 1 - s) : s;
                    const float4* h4 = (const float4*)h0s[d0];
                    float a0 = 0.f, a1 = 0.f, a2 = 0.f, a3 = 0.f;
                    #pragma unroll
                    for (int k = 0; k < 16; ++k) {
                        float4 hv = h4[k];
                        a0 = fmaf(r[4*k],   hv.x, a0);
                        a1 = fmaf(r[4*k+1], hv.y, a1);
                        a2 = fmaf(r[4*k+2], hv.z, a2);
                        a3 = fmaf(r[4*k+3], hv.w, a3);
                    }
                    const float acc = bias_ + wx0 * xbuf[i & 1][orow][0] + wx1 * xbuf[i & 1][orow][1]
                                    + ((a0 + a1) + (a2 + a3));
                    g0[d0][j0] = ((j0 >> 6) == 2) ? tanh_f(acc) : sigm(acc);
                }
            } else {  // L1
                if (s == 0 && tid >= 128 && tid < 144 && (i + 3) < NCH) {
                    const int acn = l1dir ? (NCH - 1 - (i + 3)) : (i + 3);
                    xpre = ((const float4*)(x + ((size_t)b * TT + (size_t)acn * CK) * 2))[tid - 128];
                }
                if (l1act) {
                    const int u = i * CK + s;
                    const float4* h4 = (const float4*)h1b[u & 1];
                    float a0 = 0.f, a1 = 0.f, a2 = 0.f, a3 = 0.f;
                    #pragma unroll
                    for (int k = 0; k < 16; ++k) {
                        float4 hv = h4[k];
                        a0 = fmaf(r[4*k],   hv.x, a0);
                        a1 = fmaf(r[4*k+1], hv.y, a1);
                        a2 = fmaf(r[4*k+2], hv.z, a2);
                        a3 = fmaf(r[4*k+3], hv.w, a3);
                    }
                    const int srow = l1dir ? (CK - 1 - s) : s;
                    const float acc = bias_ + xg1[i & 1][srow][tid] + ((a0 + a1) + (a2 + a3));
                    g1[tid] = ((tid >> 6) == 2) ? tanh_f(acc) : sigm(acc);
                    // logit wave (rows 64..127 = wave 1): emit h after step u-1
                    if (tid >= 64 && tid < 128 && u > 0) {
                        const float hv = h1b[u & 1][tid - 64];
                        float p0 = hv * fw0, p1 = hv * fw1;
                        #pragma unroll
                        for (int d_ = 32; d_ > 0; d_ >>= 1) { p0 += __shfl_xor(p0, d_); p1 += __shfl_xor(p1, d_); }
                        if (tid == 64) {
                            const int tp = l1dir ? (TT - u) : (u - 1);
                            *(float2*)(plog + (((size_t)l1dir * BATCH + b) * TT + tp) * 2) = make_float2(p0, p1);
                        }
                    }
                }
            }
            __syncthreads();
            // ======== phase B ========
            if (isL1) {
                if (l1act && tid < 64) {
                    const int u = i * CK + s;
                    const float iv = g1[tid], fv = g1[64 + tid], gg = g1[128 + tid], ov = g1[192 + tid];
                    c1 = fv * c1 + iv * gg;
                    h1b[(u + 1) & 1][tid] = ov * tanh_f(c1);
                }
                if (s == CK - 1 && tid >= 128 && tid < 144 && (i + 3) < NCH)
                    ((float4*)xbuf[(i + 1) & 1])[tid - 128] = xpre;
            } else if (isL0) {
                if (l0act && j0 < 64) {
                    const float iv = g0[d0][j0], fv = g0[d0][64 + j0], gg = g0[d0][128 + j0], ov = g0[d0][192 + j0];
                    c0 = fv * c0 + iv * gg;
                    const float hv = ov * tanh_f(c0);
                    const int orow = d0 ? (CK - 1 - s) : s;
                    h0buf[hbL0][orow][d0 * 64 + j0] = hv;
                    if (s == CK - 1 && (i + 3) < NCH) { h0s[d0][j0] = ckh; c0 = ckc; }
                    else h0s[d0][j0] = hv;
                }
            }
            __syncthreads();
        }
    }
    // final logit (u = TT): h1b[TT&1] = h1b[0]
    if (isL1 && tid >= 64 && tid < 128) {
        const float hv = h1b[0][tid - 64];
        float p0 = hv * fw0, p1 = hv * fw1;
        #pragma unroll
        for (int d_ = 32; d_ > 0; d_ >>= 1) { p0 += __shfl_xor(p0, d_); p1 += __shfl_xor(p1, d_); }
        if (tid == 64) {
            const int tp = l1dir ? 0 : (TT - 1);
            *(float2*)(plog + (((size_t)l1dir * BATCH + b) * TT + tp) * 2) = make_float2(p0, p1);
        }
    }
}

// ---------------- Kernel C: fused Viterbi (max-plus parallel scan + backtrack) ----------------
__device__ __forceinline__ unsigned long long shfl_u64(unsigned long long v, int src) {
    unsigned int lo = (unsigned int)v, hi = (unsigned int)(v >> 32);
    lo = __shfl(lo, src); hi = __shfl(hi, src);
    return ((unsigned long long)hi << 32) | lo;
}

__global__ __launch_bounds__(64, 1) void viterbi_k(
    const float* __restrict__ plog, const float* __restrict__ fc_b,
    const float* __restrict__ trans, const float* __restrict__ startv,
    const float* __restrict__ endv, int* __restrict__ out)
{
    const int b = blockIdx.x;
    const int lane = threadIdx.x;
    __shared__ __align__(16) float2 e_lds[64][65];   // [t&63][t>>6], padded

    const float fb0 = fc_b[0], fb1 = fc_b[1];
    const float* pf = plog + ((size_t)(0 * BATCH + b) * TT) * 2;
    const float* pb = plog + ((size_t)(1 * BATCH + b) * TT) * 2;
    for (int r = 0; r < 32; ++r) {
        const int i4 = r * 64 + lane;            // covers t = 2*i4, 2*i4+1
        float4 a = ((const float4*)pf)[i4];
        float4 cc = ((const float4*)pb)[i4];
        const int t0 = 2 * i4, t1 = t0 + 1;
        e_lds[t0 & 63][t0 >> 6] = make_float2(a.x + cc.x + fb0, a.y + cc.y + fb1);
        e_lds[t1 & 63][t1 >> 6] = make_float2(a.z + cc.z + fb0, a.w + cc.w + fb1);
    }
    __syncthreads();
    const float tr00 = trans[0], tr01 = trans[1], tr10 = trans[2], tr11 = trans[3];
    const float2 e0 = e_lds[0][0];
    const float s00 = startv[0] + e0.x, s01 = startv[1] + e0.y;   // score at t=0

    const int lo = lane * 64;
    const int hi = (lane == 63) ? (TT - 1) : (lo + 64);
    // pass 1: chunk max-plus matrix A (maps score@lo -> score@hi)
    float a00, a01, a10, a11;
    {
        const float2 ee = e_lds[(lo + 1) & 63][(lo + 1) >> 6];
        a00 = tr00 + ee.x; a01 = tr01 + ee.y; a10 = tr10 + ee.x; a11 = tr11 + ee.y;
    }
    for (int t = lo + 2; t <= hi; ++t) {
        const float2 ee = e_lds[t & 63][t >> 6];
        const float n00 = fmaxf(a00 + tr00, a01 + tr10) + ee.x;
        const float n01 = fmaxf(a00 + tr01, a01 + tr11) + ee.y;
        const float n10 = fmaxf(a10 + tr00, a11 + tr10) + ee.x;
        const float n11 = fmaxf(a10 + tr01, a11 + tr11) + ee.y;
        a00 = n00; a01 = n01; a10 = n10; a11 = n11;
    }
    // inclusive scan: lane i -> A_0 ∘ ... ∘ A_i
    #pragma unroll
    for (int d = 1; d < 64; d <<= 1) {
        const float o00 = __shfl_up(a00, d), o01 = __shfl_up(a01, d);
        const float o10 = __shfl_up(a10, d), o11 = __shfl_up(a11, d);
        if (lane >= d) {
            const float n00 = fmaxf(o00 + a00, o01 + a10);
            const float n01 = fmaxf(o00 + a01, o01 + a11);
            const float n10 = fmaxf(o10 + a00, o11 + a10);
            const float n11 = fmaxf(o10 + a01, o11 + a11);
            a00 = n00; a01 = n01; a10 = n10; a11 = n11;
        }
    }
    // entry score at t=lo
    const float p00 = __shfl_up(a00, 1), p01 = __shfl_up(a01, 1);
    const float p10 = __shfl_up(a10, 1), p11 = __shfl_up(a11, 1);
    float s0, s1;
    if (lane == 0) { s0 = s00; s1 = s01; }
    else { s0 = fmaxf(s00 + p00, s01 + p10); s1 = fmaxf(s00 + p01, s01 + p11); }
    // re-walk, record bp bits
    unsigned long long m0 = 0ull, m1 = 0ull;
    for (int t = lo + 1; t <= hi; ++t) {
        const float2 ee = e_lds[t & 63][t >> 6];
        const float c00 = s0 + tr00, c10 = s1 + tr10;
        const float c01 = s0 + tr01, c11 = s1 + tr11;
        const int bp0 = c10 > c00, bp1 = c11 > c01;   // strict >: first-index tiebreak
        s0 = (bp0 ? c10 : c00) + ee.x;
        s1 = (bp1 ? c11 : c01) + ee.y;
        m0 |= (unsigned long long)bp0 << (t - lo - 1);
        m1 |= (unsigned long long)bp1 << (t - lo - 1);
    }
    int last;
    {
        const int lt = (s1 + endv[1]) > (s0 + endv[0]);
        last = __shfl(lt, 63);
    }
    // chunk map F: tag@hi -> tag@lo
    int f0 = 0, f1 = 1;
    for (int t = hi; t > lo; --t) {
        const int s_ = t - lo - 1;
        f0 = (int)(((f0 ? m1 : m0) >> s_) & 1ull);
        f1 = (int)(((f1 ? m1 : m0) >> s_) & 1ull);
    }
    int mm = f0 | (f1 << 1);
    // suffix scan: G_i = F_i ∘ G_{i+d}
    #pragma unroll
    for (int d = 1; d < 64; d <<= 1) {
        const int mo = __shfl_down(mm, d);
        if (lane + d < 64) {
            const int r0 = (mm >> (mo & 1)) & 1;
            const int r1 = (mm >> ((mo >> 1) & 1)) & 1;
            mm = r0 | (r1 << 1);
        }
    }
    const int gn = __shfl_down(mm, 1);
    int cur = (lane == 63) ? last : ((gn >> last) & 1);   // tag at t=hi
    unsigned long long tagm = 0ull;
    if (lane == 63) tagm |= (unsigned long long)last << 63;
    for (int t = hi; t > lo; --t) {
        const int s_ = t - lo - 1;
        cur = (int)(((cur ? m1 : m0) >> s_) & 1ull);
        tagm |= (unsigned long long)cur << s_;
    }
    int* ob = out + (size_t)b * TT;
    for (int r = 0; r < 64; ++r) {
        const unsigned long long mr = shfl_u64(tagm, r);
        ob[r * 64 + lane] = (int)((mr >> lane) & 1ull);
    }
}

extern "C" void kernel_launch(void* const* d_in, const int* in_sizes, int n_in,
                              void* d_out, int out_size, void* d_ws, size_t ws_size,
                              hipStream_t stream) {
    const float* x      = (const float*)d_in[0];
    const float* w_ih0  = (const float*)d_in[1];
    const float* w_hh0  = (const float*)d_in[2];
    const float* b_ih0  = (const float*)d_in[3];
    const float* b_hh0  = (const float*)d_in[4];
    const float* w_ih1  = (const float*)d_in[5];
    const float* w_hh1  = (const float*)d_in[6];
    const float* b_ih1  = (const float*)d_in[7];
    const float* b_hh1  = (const float*)d_in[8];
    const float* fc_w   = (const float*)d_in[9];
    const float* fc_b   = (const float*)d_in[10];
    const float* trans  = (const float*)d_in[11];
    const float* startv = (const float*)d_in[12];
    const float* endv   = (const float*)d_in[13];

    char* ws = (char*)d_ws;
    const size_t ckpt_bytes = (size_t)2 * BATCH * NSLOT * 128 * 4;   // ~16.9 MB
    float* ckpt = (float*)ws;
    float* plog = (float*)(ws + ckpt_bytes);                          // 8 MB

    lstm_ckpt<<<256, 512, 0, stream>>>(x, w_ih0, w_hh0, b_ih0, b_hh0, ckpt);
    lstm_fused1<<<256, 1024, 0, stream>>>(x, w_ih0, w_hh0, b_ih0, b_hh0,
                                          w_ih1, w_hh1, b_ih1, b_hh1,
                                          fc_w, ckpt, plog);
    viterbi_k<<<128, 64, 0, stream>>>(plog, fc_b, trans, startv, endv, (int*)d_out);
}

// Round 5
// 8247.725 us; speedup vs baseline: 1.4104x; 1.0034x over previous
//
#include <hip/hip_runtime.h>

#define TT 4096
#define BATCH 128
#define HID 64
#define CK 32              // chunk size
#define NCH (TT / CK)      // 128 chunks
#define NSLOT (NCH + 1)    // 129 checkpoint slots per (dir,b)

__device__ __forceinline__ float sigm(float x) { return 1.f / (1.f + expf(-x)); }
__device__ __forceinline__ float tanh_f(float x) { float e = expf(2.f * x); return 1.f - 2.f / (e + 1.f); }

// ---------------- Kernel A: layer-0 pass, 2 threads/row, store (h,c) ckpt every CK steps ----------------
// __launch_bounds__(512, 2): 2 waves/EU min -> VGPR budget 128 (proven in R3), wv[32]+temps resident.
__global__ __launch_bounds__(512, 2) void lstm_ckpt(
    const float* __restrict__ x,      // [B][T][2]
    const float* __restrict__ w_ih,   // [2][256][2]
    const float* __restrict__ w_hh,   // [2][256][64]
    const float* __restrict__ b_ih, const float* __restrict__ b_hh,
    float* __restrict__ ckpt)         // [2][B][NSLOT][128] (h:0..63, c:64..127)
{
    const int blk = blockIdx.x;
    const int dir = blk & 1;
    const int b   = blk >> 1;
    const int tid = threadIdx.x;
    const int row = tid >> 1, half = tid & 1;

    __shared__ __align__(16) float xs[TT * 2];
    __shared__ __align__(16) float h_lds[HID];
    __shared__ __align__(16) float g_lds[256];

    {   // stage x[b] (32 KB)
        const float4* src = (const float4*)(x + (size_t)b * TT * 2);
        float4* dst = (float4*)xs;
        for (int rr = tid; rr < 2048; rr += 512) dst[rr] = src[rr];
    }
    const int grow = dir * 256 + row;
    float wv[32];
    {
        const float4* wr = (const float4*)(w_hh + (size_t)grow * 64) + half * 8;
        #pragma unroll
        for (int k = 0; k < 8; ++k) {
            float4 v = wr[k];
            wv[4*k] = v.x; wv[4*k+1] = v.y; wv[4*k+2] = v.z; wv[4*k+3] = v.w;
        }
    }
    const float wx0 = half ? 0.f : w_ih[grow * 2 + 0];
    const float wx1 = half ? 0.f : w_ih[grow * 2 + 1];
    const float bias = half ? 0.f : (b_ih[grow] + b_hh[grow]);
    const int gtype = row >> 6;
    float c = 0.f, hreg = 0.f;
    if (tid < HID) h_lds[tid] = 0.f;
    __syncthreads();

    for (int t = 0; t < TT; ++t) {
        const int tt = dir ? (TT - 1 - t) : t;
        if (tid < HID) {   // state BEFORE processing tt
            const int bnum = dir ? (tt + 1) : tt;
            if ((bnum & (CK - 1)) == 0) {
                float* cp = ckpt + (((size_t)(dir * BATCH + b) * NSLOT + (bnum >> 5)) << 7);
                cp[tid] = hreg; cp[HID + tid] = c;
            }
        }
        const float4* h4 = (const float4*)h_lds + half * 8;
        float a0 = 0.f, a1 = 0.f, a2 = 0.f, a3 = 0.f;
        #pragma unroll
        for (int k = 0; k < 8; ++k) {
            float4 hv = h4[k];
            a0 = fmaf(wv[4*k],   hv.x, a0);
            a1 = fmaf(wv[4*k+1], hv.y, a1);
            a2 = fmaf(wv[4*k+2], hv.z, a2);
            a3 = fmaf(wv[4*k+3], hv.w, a3);
        }
        float tot = (a0 + a1) + (a2 + a3);
        tot += __shfl_xor(tot, 1);
        if (half == 0) {
            const float acc = tot + bias + wx0 * xs[tt * 2] + wx1 * xs[tt * 2 + 1];
            g_lds[row] = (gtype == 2) ? tanh_f(acc) : sigm(acc);
        }
        __syncthreads();
        if (tid < HID) {
            const float iv = g_lds[tid], fv = g_lds[64 + tid], gg = g_lds[128 + tid], ov = g_lds[192 + tid];
            c = fv * c + iv * gg;
            hreg = ov * tanh_f(c);
            h_lds[tid] = hreg;
        }
        __syncthreads();
    }
}

// ---------------- Kernel B: fused L1-serial + chunk GEMM (wi1*h0) + L0 recompute + logits ----------------
// 1024 threads: [0,256) L1-serial (wh1[64]); [256,768) L0 (wh0[64]+wx[2]); [768,1024) GEMM (acc[32]).
// __launch_bounds__(1024, 4): 4 waves/EU -> VGPR budget 128 (LDS already caps at 1 block/CU = 16 waves).
__global__ __launch_bounds__(1024, 4) void lstm_fused1(
    const float* __restrict__ x,
    const float* __restrict__ w_ih0, const float* __restrict__ w_hh0,
    const float* __restrict__ b_ih0, const float* __restrict__ b_hh0,
    const float* __restrict__ w_ih1, const float* __restrict__ w_hh1,
    const float* __restrict__ b_ih1, const float* __restrict__ b_hh1,
    const float* __restrict__ fc_w,  const float* __restrict__ ckpt,
    float* __restrict__ plog)        // [2][B][T][2]
{
    const int blk = blockIdx.x;
    const int l1dir = blk & 1;
    const int b = blk >> 1;
    const int tid = threadIdx.x;

    __shared__ __align__(16) float h0buf[2][CK][128];   // 32 KB
    __shared__ __align__(16) float xg1[2][CK][256];     // 64 KB
    __shared__ __align__(16) float xbuf[2][CK][2];
    __shared__ __align__(16) float g1[256];
    __shared__ __align__(16) float g0[2][256];
    __shared__ __align__(16) float h1b[2][HID];
    __shared__ __align__(16) float h0s[2][HID];

    const bool isL1 = tid < 256;
    const bool isL0 = (tid >= 256) && (tid < 768);
    const bool isG  = tid >= 768;
    const int q0 = tid - 256;
    const int d0 = (q0 >> 8) & 1;   // L0 dir
    const int j0 = q0 & 255;        // L0 gate row
    const int jg = (tid - 768) & 255;

    float r[64];                    // L1/L0: weights; GEMM: r[0..31] accumulators
    float bias_ = 0.f, wx0 = 0.f, wx1 = 0.f, fw0 = 0.f, fw1 = 0.f;
    float c1 = 0.f, c0 = 0.f, ckh = 0.f, ckc = 0.f;
    float4 xpre = make_float4(0.f, 0.f, 0.f, 0.f);
    float4 wc = make_float4(0.f, 0.f, 0.f, 0.f);
    const float4* wip4 = (const float4*)(w_ih1 + (size_t)(l1dir * 256 + jg) * 128);

    if (isL1) {
        const int grow = l1dir * 256 + tid;
        const float4* wr = (const float4*)(w_hh1 + (size_t)grow * 64);
        #pragma unroll
        for (int k = 0; k < 16; ++k) {
            float4 v = wr[k];
            r[4*k] = v.x; r[4*k+1] = v.y; r[4*k+2] = v.z; r[4*k+3] = v.w;
        }
        bias_ = b_ih1[grow] + b_hh1[grow];
        if (tid >= 64 && tid < 128) {
            fw0 = fc_w[l1dir * 64 + (tid - 64)];
            fw1 = fc_w[128 + l1dir * 64 + (tid - 64)];
        }
    } else if (isL0) {
        const int grow = d0 * 256 + j0;
        const float4* wr = (const float4*)(w_hh0 + (size_t)grow * 64);
        #pragma unroll
        for (int k = 0; k < 16; ++k) {
            float4 v = wr[k];
            r[4*k] = v.x; r[4*k+1] = v.y; r[4*k+2] = v.z; r[4*k+3] = v.w;
        }
        wx0 = w_ih0[grow * 2 + 0];
        wx1 = w_ih0[grow * 2 + 1];
        bias_ = b_ih0[grow] + b_hh0[grow];
    } else {
        #pragma unroll
        for (int k = 0; k < 32; ++k) r[k] = 0.f;
        wc = wip4[0];
    }

    // init: h1 state, chunk-0 ckpt, chunk-0 x
    if (tid < HID) { h1b[0][tid] = 0.f; h1b[1][tid] = 0.f; }
    {
        const int ac0 = l1dir ? (NCH - 1) : 0;
        if (tid < 16)
            ((float4*)xbuf[0])[tid] = ((const float4*)(x + ((size_t)b * TT + (size_t)ac0 * CK) * 2))[tid];
        if (isL0 && j0 < 64) {
            const int slot = d0 ? (ac0 + 1) : ac0;
            const float* cp = ckpt + (((size_t)(d0 * BATCH + b) * NSLOT + slot) << 7);
            h0s[d0][j0] = cp[j0];
            c0 = cp[HID + j0];
        }
    }
    __syncthreads();

    // phase i: L1 consumes seq-chunk i; GEMM builds xg1 for chunk i+1 from h0buf[(i+1)&1];
    //          L0 computes chunk i+2 into h0buf[i&1]; prefetch ckpt/x for chunk i+3.
    for (int i = -2; i < NCH; ++i) {
        const bool l1act = i >= 0;
        const bool gact  = (i + 1 >= 0) && (i + 1 < NCH);
        const bool l0act = (i + 2) < NCH;
        const int hbL0 = i & 1;
        const int hbG  = (i + 1) & 1;
        for (int s = 0; s < CK; ++s) {
            // ======== phase A ========
            if (isG) {
                if (gact) {
                    float4 wn = wip4[(s + 1) & (CK - 1)];
                    const float4* hb = (const float4*)&h0buf[hbG][0][0] + s;   // row stride 32 float4
                    #pragma unroll
                    for (int s2 = 0; s2 < 32; ++s2) {
                        float4 hv = hb[s2 * 32];
                        float t0 = r[s2];
                        t0 = fmaf(wc.x, hv.x, t0);
                        t0 = fmaf(wc.y, hv.y, t0);
                        t0 = fmaf(wc.z, hv.z, t0);
                        t0 = fmaf(wc.w, hv.w, t0);
                        r[s2] = t0;
                    }
                    if (s == CK - 1) {
                        #pragma unroll
                        for (int s2 = 0; s2 < 32; ++s2) { xg1[hbG][s2][jg] = r[s2]; r[s2] = 0.f; }
                    }
                    wc = wn;
                }
            } else if (isL0) {
                if (s == 0 && j0 < 64 && (i + 3) < NCH) {
                    const int acn = l1dir ? (NCH - 1 - (i + 3)) : (i + 3);
                    const int slot = d0 ? (acn + 1) : acn;
                    const float* cp = ckpt + (((size_t)(d0 * BATCH + b) * NSLOT + slot) << 7);
                    ckh = cp[j0]; ckc = cp[HID + j0];
                }
                if (l0act) {
                    const int orow = d0 ? (CK - 1 - s) : s;
                    const float4* h4 = (const float4*)h0s[d0];
                    float a0 = 0.f, a1 = 0.f, a2 = 0.f, a3 = 0.f;
                    #pragma unroll
                    for (int k = 0; k < 16; ++k) {
                        float4 hv = h4[k];
                        a0 = fmaf(r[4*k],   hv.x, a0);
                        a1 = fmaf(r[4*k+1], hv.y, a1);
                        a2 = fmaf(r[4*k+2], hv.z, a2);
                        a3 = fmaf(r[4*k+3], hv.w, a3);
                    }
                    const float acc = bias_ + wx0 * xbuf[i & 1][orow][0] + wx1 * xbuf[i & 1][orow][1]
                                    + ((a0 + a1) + (a2 + a3));
                    g0[d0][j0] = ((j0 >> 6) == 2) ? tanh_f(acc) : sigm(acc);
                }
            } else {  // L1
                if (s == 0 && tid >= 128 && tid < 144 && (i + 3) < NCH) {
                    const int acn = l1dir ? (NCH - 1 - (i + 3)) : (i + 3);
                    xpre = ((const float4*)(x + ((size_t)b * TT + (size_t)acn * CK) * 2))[tid - 128];
                }
                if (l1act) {
                    const int u = i * CK + s;
                    const float4* h4 = (const float4*)h1b[u & 1];
                    float a0 = 0.f, a1 = 0.f, a2 = 0.f, a3 = 0.f;
                    #pragma unroll
                    for (int k = 0; k < 16; ++k) {
                        float4 hv = h4[k];
                        a0 = fmaf(r[4*k],   hv.x, a0);
                        a1 = fmaf(r[4*k+1], hv.y, a1);
                        a2 = fmaf(r[4*k+2], hv.z, a2);
                        a3 = fmaf(r[4*k+3], hv.w, a3);
                    }
                    const int srow = l1dir ? (CK - 1 - s) : s;
                    const float acc = bias_ + xg1[i & 1][srow][tid] + ((a0 + a1) + (a2 + a3));
                    g1[tid] = ((tid >> 6) == 2) ? tanh_f(acc) : sigm(acc);
                    // logit wave (rows 64..127 = wave 1): emit h after step u-1
                    if (tid >= 64 && tid < 128 && u > 0) {
                        const float hv = h1b[u & 1][tid - 64];
                        float p0 = hv * fw0, p1 = hv * fw1;
                        #pragma unroll
                        for (int d_ = 32; d_ > 0; d_ >>= 1) { p0 += __shfl_xor(p0, d_); p1 += __shfl_xor(p1, d_); }
                        if (tid == 64) {
                            const int tp = l1dir ? (TT - u) : (u - 1);
                            *(float2*)(plog + (((size_t)l1dir * BATCH + b) * TT + tp) * 2) = make_float2(p0, p1);
                        }
                    }
                }
            }
            __syncthreads();
            // ======== phase B ========
            if (isL1) {
                if (l1act && tid < 64) {
                    const int u = i * CK + s;
                    const float iv = g1[tid], fv = g1[64 + tid], gg = g1[128 + tid], ov = g1[192 + tid];
                    c1 = fv * c1 + iv * gg;
                    h1b[(u + 1) & 1][tid] = ov * tanh_f(c1);
                }
                if (s == CK - 1 && tid >= 128 && tid < 144 && (i + 3) < NCH)
                    ((float4*)xbuf[(i + 1) & 1])[tid - 128] = xpre;
            } else if (isL0) {
                if (l0act && j0 < 64) {
                    const float iv = g0[d0][j0], fv = g0[d0][64 + j0], gg = g0[d0][128 + j0], ov = g0[d0][192 + j0];
                    c0 = fv * c0 + iv * gg;
                    const float hv = ov * tanh_f(c0);
                    const int orow = d0 ? (CK - 1 - s) : s;
                    h0buf[hbL0][orow][d0 * 64 + j0] = hv;
                    if (s == CK - 1 && (i + 3) < NCH) { h0s[d0][j0] = ckh; c0 = ckc; }
                    else h0s[d0][j0] = hv;
                }
            }
            __syncthreads();
        }
    }
    // final logit (u = TT): h1b[TT&1] = h1b[0]
    if (isL1 && tid >= 64 && tid < 128) {
        const float hv = h1b[0][tid - 64];
        float p0 = hv * fw0, p1 = hv * fw1;
        #pragma unroll
        for (int d_ = 32; d_ > 0; d_ >>= 1) { p0 += __shfl_xor(p0, d_); p1 += __shfl_xor(p1, d_); }
        if (tid == 64) {
            const int tp = l1dir ? 0 : (TT - 1);
            *(float2*)(plog + (((size_t)l1dir * BATCH + b) * TT + tp) * 2) = make_float2(p0, p1);
        }
    }
}

// ---------------- Kernel C: fused Viterbi (max-plus parallel scan + backtrack) ----------------
__device__ __forceinline__ unsigned long long shfl_u64(unsigned long long v, int src) {
    unsigned int lo = (unsigned int)v, hi = (unsigned int)(v >> 32);
    lo = __shfl(lo, src); hi = __shfl(hi, src);
    return ((unsigned long long)hi << 32) | lo;
}

__global__ __launch_bounds__(64, 1) void viterbi_k(
    const float* __restrict__ plog, const float* __restrict__ fc_b,
    const float* __restrict__ trans, const float* __restrict__ startv,
    const float* __restrict__ endv, int* __restrict__ out)
{
    const int b = blockIdx.x;
    const int lane = threadIdx.x;
    __shared__ __align__(16) float2 e_lds[64][65];   // [t&63][t>>6], padded

    const float fb0 = fc_b[0], fb1 = fc_b[1];
    const float* pf = plog + ((size_t)(0 * BATCH + b) * TT) * 2;
    const float* pb = plog + ((size_t)(1 * BATCH + b) * TT) * 2;
    for (int r = 0; r < 32; ++r) {
        const int i4 = r * 64 + lane;            // covers t = 2*i4, 2*i4+1
        float4 a = ((const float4*)pf)[i4];
        float4 cc = ((const float4*)pb)[i4];
        const int t0 = 2 * i4, t1 = t0 + 1;
        e_lds[t0 & 63][t0 >> 6] = make_float2(a.x + cc.x + fb0, a.y + cc.y + fb1);
        e_lds[t1 & 63][t1 >> 6] = make_float2(a.z + cc.z + fb0, a.w + cc.w + fb1);
    }
    __syncthreads();
    const float tr00 = trans[0], tr01 = trans[1], tr10 = trans[2], tr11 = trans[3];
    const float2 e0 = e_lds[0][0];
    const float s00 = startv[0] + e0.x, s01 = startv[1] + e0.y;   // score at t=0

    const int lo = lane * 64;
    const int hi = (lane == 63) ? (TT - 1) : (lo + 64);
    // pass 1: chunk max-plus matrix A (maps score@lo -> score@hi)
    float a00, a01, a10, a11;
    {
        const float2 ee = e_lds[(lo + 1) & 63][(lo + 1) >> 6];
        a00 = tr00 + ee.x; a01 = tr01 + ee.y; a10 = tr10 + ee.x; a11 = tr11 + ee.y;
    }
    for (int t = lo + 2; t <= hi; ++t) {
        const float2 ee = e_lds[t & 63][t >> 6];
        const float n00 = fmaxf(a00 + tr00, a01 + tr10) + ee.x;
        const float n01 = fmaxf(a00 + tr01, a01 + tr11) + ee.y;
        const float n10 = fmaxf(a10 + tr00, a11 + tr10) + ee.x;
        const float n11 = fmaxf(a10 + tr01, a11 + tr11) + ee.y;
        a00 = n00; a01 = n01; a10 = n10; a11 = n11;
    }
    // inclusive scan: lane i -> A_0 ∘ ... ∘ A_i
    #pragma unroll
    for (int d = 1; d < 64; d <<= 1) {
        const float o00 = __shfl_up(a00, d), o01 = __shfl_up(a01, d);
        const float o10 = __shfl_up(a10, d), o11 = __shfl_up(a11, d);
        if (lane >= d) {
            const float n00 = fmaxf(o00 + a00, o01 + a10);
            const float n01 = fmaxf(o00 + a01, o01 + a11);
            const float n10 = fmaxf(o10 + a00, o11 + a10);
            const float n11 = fmaxf(o10 + a01, o11 + a11);
            a00 = n00; a01 = n01; a10 = n10; a11 = n11;
        }
    }
    // entry score at t=lo
    const float p00 = __shfl_up(a00, 1), p01 = __shfl_up(a01, 1);
    const float p10 = __shfl_up(a10, 1), p11 = __shfl_up(a11, 1);
    float s0, s1;
    if (lane == 0) { s0 = s00; s1 = s01; }
    else { s0 = fmaxf(s00 + p00, s01 + p10); s1 = fmaxf(s00 + p01, s01 + p11); }
    // re-walk, record bp bits
    unsigned long long m0 = 0ull, m1 = 0ull;
    for (int t = lo + 1; t <= hi; ++t) {
        const float2 ee = e_lds[t & 63][t >> 6];
        const float c00 = s0 + tr00, c10 = s1 + tr10;
        const float c01 = s0 + tr01, c11 = s1 + tr11;
        const int bp0 = c10 > c00, bp1 = c11 > c01;   // strict >: first-index tiebreak
        s0 = (bp0 ? c10 : c00) + ee.x;
        s1 = (bp1 ? c11 : c01) + ee.y;
        m0 |= (unsigned long long)bp0 << (t - lo - 1);
        m1 |= (unsigned long long)bp1 << (t - lo - 1);
    }
    int last;
    {
        const int lt = (s1 + endv[1]) > (s0 + endv[0]);
        last = __shfl(lt, 63);
    }
    // chunk map F: tag@hi -> tag@lo
    int f0 = 0, f1 = 1;
    for (int t = hi; t > lo; --t) {
        const int s_ = t - lo - 1;
        f0 = (int)(((f0 ? m1 : m0) >> s_) & 1ull);
        f1 = (int)(((f1 ? m1 : m0) >> s_) & 1ull);
    }
    int mm = f0 | (f1 << 1);
    // suffix scan: G_i = F_i ∘ G_{i+d}
    #pragma unroll
    for (int d = 1; d < 64; d <<= 1) {
        const int mo = __shfl_down(mm, d);
        if (lane + d < 64) {
            const int r0 = (mm >> (mo & 1)) & 1;
            const int r1 = (mm >> ((mo >> 1) & 1)) & 1;
            mm = r0 | (r1 << 1);
        }
    }
    const int gn = __shfl_down(mm, 1);
    int cur = (lane == 63) ? last : ((gn >> last) & 1);   // tag at t=hi
    unsigned long long tagm = 0ull;
    if (lane == 63) tagm |= (unsigned long long)last << 63;
    for (int t = hi; t > lo; --t) {
        const int s_ = t - lo - 1;
        cur = (int)(((cur ? m1 : m0) >> s_) & 1ull);
        tagm |= (unsigned long long)cur << s_;
    }
    int* ob = out + (size_t)b * TT;
    for (int r = 0; r < 64; ++r) {
        const unsigned long long mr = shfl_u64(tagm, r);
        ob[r * 64 + lane] = (int)((mr >> lane) & 1ull);
    }
}

extern "C" void kernel_launch(void* const* d_in, const int* in_sizes, int n_in,
                              void* d_out, int out_size, void* d_ws, size_t ws_size,
                              hipStream_t stream) {
    const float* x      = (const float*)d_in[0];
    const float* w_ih0  = (const float*)d_in[1];
    const float* w_hh0  = (const float*)d_in[2];
    const float* b_ih0  = (const float*)d_in[3];
    const float* b_hh0  = (const float*)d_in[4];
    const float* w_ih1  = (const float*)d_in[5];
    const float* w_hh1  = (const float*)d_in[6];
    const float* b_ih1  = (const float*)d_in[7];
    const float* b_hh1  = (const float*)d_in[8];
    const float* fc_w   = (const float*)d_in[9];
    const float* fc_b   = (const float*)d_in[10];
    const float* trans  = (const float*)d_in[11];
    const float* startv = (const float*)d_in[12];
    const float* endv   = (const float*)d_in[13];

    char* ws = (char*)d_ws;
    const size_t ckpt_bytes = (size_t)2 * BATCH * NSLOT * 128 * 4;   // ~16.9 MB
    float* ckpt = (float*)ws;
    float* plog = (float*)(ws + ckpt_bytes);                          // 8 MB

    lstm_ckpt<<<256, 512, 0, stream>>>(x, w_ih0, w_hh0, b_ih0, b_hh0, ckpt);
    lstm_fused1<<<256, 1024, 0, stream>>>(x, w_ih0, w_hh0, b_ih0, b_hh0,
                                          w_ih1, w_hh1, b_ih1, b_hh1,
                                          fc_w, ckpt, plog);
    viterbi_k<<<128, 64, 0, stream>>>(plog, fc_b, trans, startv, endv, (int*)d_out);
}